// Round 13
// baseline (1655.213 us; speedup 1.0000x reference)
//
#include <hip/hip_runtime.h>
#include <hip/hip_bf16.h>

typedef __hip_bfloat16 bf16;
typedef _Float16 half_t;
typedef __attribute__((ext_vector_type(8))) _Float16 half8;
typedef __attribute__((ext_vector_type(4))) float f32x4;

#define LN_EPS 1e-5f

static constexpr int Dk     = 256;   // model dim
static constexpr int Tk     = 2048;  // seq len
static constexpr int BTk    = 8192;  // B*T
static constexpr int MHk    = 2048;  // N/H
static constexpr int Nk     = 8192;  // hidden
static constexpr int LAYERS = 6;
static constexpr long long TD  = (long long)Tk * Dk;    // 524288
static constexpr long long BTD = (long long)BTk * Dk;   // 2097152
static constexpr long long TT  = (long long)Tk * Tk;    // 4194304

// LDS k-octet XOR swizzle (verified r10/r11: SQ_LDS_BANK_CONFLICT -> 0):
// staging lane j sources global k-octet (j&3)^((j>>3)&3); reader at row R,
// quad q uses slot q^((R>>1)&3).
#define SKQ(t) ((((t) & 3) ^ (((t) >> 3) & 3)) * 8)

// ---------------------------------------------------------------------------
__device__ __forceinline__ float wave_reduce(float v) {
#pragma unroll
    for (int o = 32; o > 0; o >>= 1) v += __shfl_down(v, o);
    return v;
}

__device__ __forceinline__ float block_sum_256(float x, float* sbuf) {
    float s = wave_reduce(x);
    int lane = threadIdx.x & 63, wv = threadIdx.x >> 6;
    if (lane == 0) sbuf[wv] = s;
    __syncthreads();
    float r = sbuf[0] + sbuf[1] + sbuf[2] + sbuf[3];
    __syncthreads();
    return r;
}

// async global->LDS, 16B/lane; LDS base wave-uniform, HW appends lane*16.
__device__ __forceinline__ void glds16(const void* g, void* lds) {
    __builtin_amdgcn_global_load_lds(
        (const __attribute__((address_space(1))) void*)g,
        (__attribute__((address_space(3))) void*)lds, 16, 0, 0);
}

// ---------------------------------------------------------------------------
// input dtype sniffer (insurance; inputs confirmed fp32)
__global__ __launch_bounds__(256) void sniff_kernel(const unsigned short* __restrict__ w,
                                                    int* __restrict__ flag) {
    __shared__ float sbuf[4];
    int tid = threadIdx.x;
    float cnt = 0.f;
    for (int i = tid; i < 1024; i += 256) {
        int e = (w[i] >> 7) & 0xFF;
        if (e >= 128) cnt += 1.f;
    }
    float tot = block_sum_256(cnt, sbuf);
    if (tid == 0) *flag = (tot > 32.f) ? 1 : 0;
}

// transpose + fp16 convert: src [R][C] (per z) -> dst [C][R] fp16
__global__ __launch_bounds__(256) void tr_cvt16_kernel(const void* __restrict__ src,
                                                       const int* __restrict__ flag,
                                                       half_t* __restrict__ dst,
                                                       int R, int C,
                                                       long long sz, long long dz) {
    __shared__ float t[32][33];
    bool f32 = (*flag != 0);
    int ct = blockIdx.x * 32, rt = blockIdx.y * 32;
    long long so = (long long)blockIdx.z * sz, dofs = (long long)blockIdx.z * dz;
    int tx = threadIdx.x & 31, ty = threadIdx.x >> 5;
#pragma unroll
    for (int i = 0; i < 4; i++) {
        long long idx = so + (long long)(rt + ty + i * 8) * C + ct + tx;
        t[ty + i * 8][tx] = f32 ? ((const float*)src)[idx] : (float)((const bf16*)src)[idx];
    }
    __syncthreads();
#pragma unroll
    for (int i = 0; i < 4; i++) {
        long long odx = dofs + (long long)(ct + ty + i * 8) * R + rt + tx;
        dst[odx] = (half_t)t[tx][ty + i * 8];
    }
}

// v32 [BT][D] fp32 -> vT [D][BT] fp16
__global__ __launch_bounds__(256) void trv_kernel(const float* __restrict__ src,
                                                  half_t* __restrict__ dst) {
    __shared__ float t[32][33];
    int ct = blockIdx.x * 32, rt = blockIdx.y * 32;
    int tx = threadIdx.x & 31, ty = threadIdx.x >> 5;
#pragma unroll
    for (int i = 0; i < 4; i++)
        t[ty + i * 8][tx] = src[(long long)(rt + ty + i * 8) * Dk + ct + tx];
    __syncthreads();
#pragma unroll
    for (int i = 0; i < 4; i++)
        dst[(long long)(ct + ty + i * 8) * BTk + rt + tx] = (half_t)t[tx][ty + i * 8];
}

// ---------------------------------------------------------------------------
// v = layernorm(wte[idx]) -> v32 fp32, vf fp16
__global__ __launch_bounds__(256) void embed_ln_kernel(const int* __restrict__ idx,
                                                       const void* __restrict__ wte,
                                                       const int* __restrict__ flag,
                                                       float* __restrict__ v,
                                                       half_t* __restrict__ vf) {
    __shared__ float sbuf[4];
    int bt = blockIdx.x, tid = threadIdx.x;
    int id = idx[bt];
    bool f32 = (*flag != 0);
    float x = f32 ? ((const float*)wte)[id * Dk + tid]
                  : (float)((const bf16*)wte)[id * Dk + tid];
    float mu = block_sum_256(x, sbuf) * (1.f / 256.f);
    float d = x - mu;
    float var = block_sum_256(d * d, sbuf) * (1.f / 256.f);
    float r = d * rsqrtf(var + LN_EPS);
    v[bt * Dk + tid] = r;
    vf[bt * Dk + tid] = (half_t)r;
}

// lnf = fp16(layernorm(sum of alive a-partials)).
// Row t (in batch): alive chunks c with c*512 <= (t & ~127).
__global__ __launch_bounds__(256) void ln_rows_kernel(const float* __restrict__ Pa,
                                                      half_t* __restrict__ of) {
    __shared__ float sbuf[4];
    int bt = blockIdx.x, tid = threadIdx.x;
    int b = bt >> 11, t = bt & (Tk - 1);
    int ncnt = ((t & ~127) >> 9) + 1;
    const float* p = Pa + ((long long)(b << 2)) * TD + (long long)t * Dk + tid;
    float x = 0.f;
    for (int c = 0; c < ncnt; c++) x += p[(long long)c * TD];
    float mu = block_sum_256(x, sbuf) * (1.f / 256.f);
    float d = x - mu;
    float var = block_sum_256(d * d, sbuf) * (1.f / 256.f);
    float r = d * rsqrtf(var + LN_EPS);
    of[bt * Dk + tid] = (half_t)r;
}

// v += layernorm(sum of 8 update-partials) -> refresh v32, vf
__global__ __launch_bounds__(256) void add_ln_kernel(const float* __restrict__ Pu,
                                                     float* __restrict__ v,
                                                     half_t* __restrict__ vf) {
    __shared__ float sbuf[4];
    int bt = blockIdx.x, tid = threadIdx.x;
    long long e = (long long)bt * Dk + tid;
    float x = 0.f;
#pragma unroll
    for (int p = 0; p < 8; p++) x += Pu[e + (long long)p * BTD];
    float mu = block_sum_256(x, sbuf) * (1.f / 256.f);
    float d = x - mu;
    float var = block_sum_256(d * d, sbuf) * (1.f / 256.f);
    float r = d * rsqrtf(var + LN_EPS);
    float nv = v[e] + r;
    v[e] = nv;
    vf[e] = (half_t)nv;
}

// RoPE from fp32 v -> qf fp16 (Q == K)
__global__ __launch_bounds__(128) void rope_kernel(const float* __restrict__ v,
                                                   half_t* __restrict__ qf) {
    int bt = blockIdx.x, i = threadIdx.x;
    int t = bt & (Tk - 1);
    float invf = powf(10000.f, -(float)i / 128.f);
    float ang = (float)t * invf;
    float s, c;
    sincosf(ang, &s, &c);
    float q1 = v[bt * Dk + i];
    float q2 = v[bt * Dk + 128 + i];
    qf[bt * Dk + i]       = (half_t)(q1 * c - q2 * s);
    qf[bt * Dk + 128 + i] = (half_t)(q2 * c + q1 * s);
}

// ---------------------------------------------------------------------------
// Energy: E[b] = tril(Qr Qr^T), fp16, 128x128 swizzled, z = batch.
// Upper blocks never read downstream -> early exit. LDS epilogue (dense stores).
__global__ __launch_bounds__(256) void gemm128e(
    const half_t* __restrict__ Q, half_t* __restrict__ E) {
    __shared__ __align__(16) half_t smem[8192];   // As | Bs, reused by epilogue
    half_t* As = smem;
    half_t* Bs = smem + 4096;
    const int tid = threadIdx.x;
    const int lane = tid & 63, wv = tid >> 6;
    const int wr = wv >> 1, wc = wv & 1;
    const int quad = lane >> 4, r = lane & 15;
    const int qsw = (quad ^ ((r >> 1) & 3)) * 8;
    const int mb = blockIdx.y * 128, nb = blockIdx.x * 128;
    if ((int)blockIdx.x > (int)blockIdx.y) return;   // never read
    const half_t* Qb = Q + (long long)blockIdx.z * TD;
    half_t* Eb = E + (long long)blockIdx.z * TT;

    f32x4 acc[4][4] = {};
    const int srow = tid >> 2, skq = SKQ(tid);
    const int wbase = (tid & 192) * 8;
    for (int k0 = 0; k0 < Dk; k0 += 32) {
#pragma unroll
        for (int rnd = 0; rnd < 2; rnd++) {
            int row = rnd * 64 + srow;
            glds16(Qb + (long long)(mb + row) * Dk + k0 + skq, As + rnd * 2048 + wbase);
            glds16(Qb + (long long)(nb + row) * Dk + k0 + skq, Bs + rnd * 2048 + wbase);
        }
        __syncthreads();
        half8 bfr[4];
#pragma unroll
        for (int ni = 0; ni < 4; ni++)
            bfr[ni] = *(const half8*)&Bs[(wc * 64 + ni * 16 + r) * 32 + qsw];
#pragma unroll
        for (int mi = 0; mi < 4; mi++) {
            half8 afr = *(const half8*)&As[(wr * 64 + mi * 16 + r) * 32 + qsw];
#pragma unroll
            for (int ni = 0; ni < 4; ni++)
                acc[mi][ni] = __builtin_amdgcn_mfma_f32_16x16x32_f16(afr, bfr[ni], acc[mi][ni], 0, 0, 0);
        }
        __syncthreads();
    }
#pragma unroll
    for (int p = 0; p < 2; p++) {
        if (wr == p) {
#pragma unroll
            for (int mi = 0; mi < 4; mi++)
#pragma unroll
                for (int ni = 0; ni < 4; ni++) {
                    int rl0 = mi * 16 + quad * 4;
                    int cl = wc * 64 + ni * 16 + r;
#pragma unroll
                    for (int rr = 0; rr < 4; rr++) {
                        int row = mb + p * 64 + rl0 + rr;
                        int col = nb + cl;
                        float val = (row < col) ? 0.f : acc[mi][ni][rr];
                        smem[(rl0 + rr) * 128 + cl] = (half_t)val;
                    }
                }
        }
        __syncthreads();
#pragma unroll
        for (int j = 0; j < 4; j++) {
            int o = j * 2048 + tid * 8;
            int rl = o >> 7, cl = o & 127;
            *(half8*)&Eb[(long long)(mb + p * 64 + rl) * Tk + nb + cl] = *(const half8*)&smem[o];
        }
        __syncthreads();
    }
}

// ---------------------------------------------------------------------------
// a-GEMM: Pa[z] = E_chunk @ V, 128x128 swizzled, split-K partial stores.
// z = b*4 + c (batch, K-chunk of 512). Dead causal chunks skipped.
__global__ __launch_bounds__(256) void gemm128a(
    const half_t* __restrict__ E, const half_t* __restrict__ vT,
    float* __restrict__ Pa) {
    __shared__ __align__(16) half_t As[128 * 32];
    __shared__ __align__(16) half_t Bs[128 * 32];
    const int tid = threadIdx.x;
    const int lane = tid & 63, wv = tid >> 6;
    const int wr = wv >> 1, wc = wv & 1;
    const int quad = lane >> 4, r = lane & 15;
    const int qsw = (quad ^ ((r >> 1) & 3)) * 8;
    const int mb = blockIdx.y * 128, nb = blockIdx.x * 128;
    const int b = blockIdx.z >> 2, c = blockIdx.z & 3;
    const int kbeg = c * 512;
    const int kend = min(mb + 128, kbeg + 512);
    if (kend <= kbeg) return;

    const half_t* Ab = E + (long long)b * TT;
    const half_t* Bb = vT + (long long)b * Tk;
    float* Pc = Pa + (long long)blockIdx.z * TD;
    f32x4 acc[4][4] = {};
    const int srow = tid >> 2, skq = SKQ(tid);
    const int wbase = (tid & 192) * 8;
    for (int k0 = kbeg; k0 < kend; k0 += 32) {
#pragma unroll
        for (int rnd = 0; rnd < 2; rnd++) {
            int row = rnd * 64 + srow;
            glds16(Ab + (long long)(mb + row) * Tk + k0 + skq, As + rnd * 2048 + wbase);
            glds16(Bb + (long long)(nb + row) * BTk + k0 + skq, Bs + rnd * 2048 + wbase);
        }
        __syncthreads();
        half8 bfr[4];
#pragma unroll
        for (int ni = 0; ni < 4; ni++)
            bfr[ni] = *(const half8*)&Bs[(wc * 64 + ni * 16 + r) * 32 + qsw];
#pragma unroll
        for (int mi = 0; mi < 4; mi++) {
            half8 afr = *(const half8*)&As[(wr * 64 + mi * 16 + r) * 32 + qsw];
#pragma unroll
            for (int ni = 0; ni < 4; ni++)
                acc[mi][ni] = __builtin_amdgcn_mfma_f32_16x16x32_f16(afr, bfr[ni], acc[mi][ni], 0, 0, 0);
        }
        __syncthreads();
    }
#pragma unroll
    for (int mi = 0; mi < 4; mi++)
#pragma unroll
        for (int ni = 0; ni < 4; ni++) {
            int row0 = mb + wr * 64 + mi * 16 + quad * 4;
            int col = nb + wc * 64 + ni * 16 + r;
#pragma unroll
            for (int rr = 0; rr < 4; rr++)
                Pc[(long long)(row0 + rr) * Dk + col] = acc[mi][ni][rr];
        }
}

// ---------------------------------------------------------------------------
// FUSED decoder: y never touches HBM.
// Grid (8 K-splits, 64 M-blocks), 512 thr (8 waves: wr=wv>>2 m-half, wc=wv&3).
// Per n-chunk of 128 (8 chunks per block): y = relu(lnf@dyT)*relu(vf@dxT)
// (K=256) -> Ys in LDS (row-XOR swizzle) -> accU += Ys @ eT_chunk (K=128).
// Epilogue: Pu[split][BT][D] fp32 partials (add_ln sums 8).
__global__ __launch_bounds__(512, 2) void fused_du(
    const half_t* __restrict__ A1,   // vf  [BT][D]
    const half_t* __restrict__ A2,   // lnf [BT][D]
    const half_t* __restrict__ dxT,  // [Nk][D]
    const half_t* __restrict__ dyT,  // [Nk][D]
    const half_t* __restrict__ eT,   // [D][Nk]
    float* __restrict__ Pu) {
    __shared__ __align__(16) half_t As1[4096];
    __shared__ __align__(16) half_t As2[4096];
    __shared__ __align__(16) half_t Bs1[4096];
    __shared__ __align__(16) half_t Bs2[4096];
    __shared__ __align__(16) half_t Ys[16384];   // y-chunk [128][128], swizzled
    __shared__ __align__(16) half_t Es[8192];    // eT chunk [256][32]
    const int tid = threadIdx.x;
    const int lane = tid & 63, wv = tid >> 6;
    const int wr = wv >> 2, wc = wv & 3;
    const int quad = lane >> 4, r = lane & 15;
    const int qsw = (quad ^ ((r >> 1) & 3)) * 8;
    const int mb = blockIdx.y * 128;
    const int nbase = blockIdx.x * 1024;
    const int srow = tid >> 2, skq = SKQ(tid);
    const int wbase = (tid & 448) * 8;

    f32x4 accU[4][4] = {};
    for (int nc = 0; nc < 8; nc++) {
        const int n0 = nbase + nc * 128;
        f32x4 accX[4][2] = {};
        f32x4 accY[4][2] = {};
        for (int k0 = 0; k0 < Dk; k0 += 32) {
            glds16(A1 + (long long)(mb + srow) * Dk + k0 + skq, As1 + wbase);
            glds16(A2 + (long long)(mb + srow) * Dk + k0 + skq, As2 + wbase);
            glds16(dxT + (long long)(n0 + srow) * Dk + k0 + skq, Bs1 + wbase);
            glds16(dyT + (long long)(n0 + srow) * Dk + k0 + skq, Bs2 + wbase);
            __syncthreads();
            half8 b1f[2], b2f[2];
#pragma unroll
            for (int ni = 0; ni < 2; ni++) {
                b1f[ni] = *(const half8*)&Bs1[(wc * 32 + ni * 16 + r) * 32 + qsw];
                b2f[ni] = *(const half8*)&Bs2[(wc * 32 + ni * 16 + r) * 32 + qsw];
            }
#pragma unroll
            for (int mi = 0; mi < 4; mi++) {
                half8 a1 = *(const half8*)&As1[(wr * 64 + mi * 16 + r) * 32 + qsw];
                half8 a2 = *(const half8*)&As2[(wr * 64 + mi * 16 + r) * 32 + qsw];
#pragma unroll
                for (int ni = 0; ni < 2; ni++) {
                    accX[mi][ni] = __builtin_amdgcn_mfma_f32_16x16x32_f16(a1, b1f[ni], accX[mi][ni], 0, 0, 0);
                    accY[mi][ni] = __builtin_amdgcn_mfma_f32_16x16x32_f16(a2, b2f[ni], accY[mi][ni], 0, 0, 0);
                }
            }
            __syncthreads();
        }
        // y-chunk -> Ys, octet XOR'd by (row&15): write conflict-free,
        // A-frag read 2-way (free).
#pragma unroll
        for (int mi = 0; mi < 4; mi++)
#pragma unroll
            for (int ni = 0; ni < 2; ni++) {
                int rl0 = wr * 64 + mi * 16 + quad * 4;
                int col = wc * 32 + ni * 16 + r;
#pragma unroll
                for (int rr = 0; rr < 4; rr++) {
                    int row = rl0 + rr;
                    float val = fmaxf(accY[mi][ni][rr], 0.f) * fmaxf(accX[mi][ni][rr], 0.f);
                    int o = ((col >> 3) ^ (row & 15)) * 8;
                    Ys[row * 128 + o + (col & 7)] = (half_t)val;
                }
            }
        __syncthreads();
        // accU += Ys[128m][128n] @ eT[256d][n-window]
#pragma unroll
        for (int kk = 0; kk < 4; kk++) {
#pragma unroll
            for (int rnd = 0; rnd < 2; rnd++)
                glds16(eT + (long long)(rnd * 128 + srow) * Nk + n0 + kk * 32 + skq,
                       Es + rnd * 4096 + wbase);
            __syncthreads();
            half8 bf[4];
#pragma unroll
            for (int ni = 0; ni < 4; ni++)
                bf[ni] = *(const half8*)&Es[(wc * 64 + ni * 16 + r) * 32 + qsw];
#pragma unroll
            for (int mi = 0; mi < 4; mi++) {
                int arow = wr * 64 + mi * 16 + r;
                half8 af = *(const half8*)&Ys[arow * 128 + (((kk * 4 + quad) ^ r)) * 8];
#pragma unroll
                for (int ni = 0; ni < 4; ni++)
                    accU[mi][ni] = __builtin_amdgcn_mfma_f32_16x16x32_f16(af, bf[ni], accU[mi][ni], 0, 0, 0);
            }
            __syncthreads();
        }
    }
    float* Pc = Pu + (long long)blockIdx.x * BTD;
#pragma unroll
    for (int mi = 0; mi < 4; mi++)
#pragma unroll
        for (int ni = 0; ni < 4; ni++) {
            int row0 = mb + wr * 64 + mi * 16 + quad * 4;
            int col = wc * 64 + ni * 16 + r;
#pragma unroll
            for (int rr = 0; rr < 4; rr++)
                Pc[(long long)(row0 + rr) * Dk + col] = accU[mi][ni][rr];
        }
}

// ---------------------------------------------------------------------------
// Plain fp16 64x64 async GEMM, swizzled, fp32 store — readout. A [M][K], B [N][K].
__global__ __launch_bounds__(256) void gemm64h(
    const half_t* __restrict__ A, int lda,
    const half_t* __restrict__ B, int ldb,
    float* __restrict__ C, int ldc, int K) {
    __shared__ __align__(16) half_t As[64 * 32];
    __shared__ __align__(16) half_t Bs[64 * 32];
    const int tid = threadIdx.x;
    const int lane = tid & 63, wv = tid >> 6;
    const int wr = wv >> 1, wc = wv & 1;
    const int quad = lane >> 4, r = lane & 15;
    const int qsw = (quad ^ ((r >> 1) & 3)) * 8;
    const int mb = blockIdx.y * 64, nb = blockIdx.x * 64;

    f32x4 acc[2][2] = {};
    const int srow = tid >> 2, skq = SKQ(tid);
    const int wbase = (tid & 192) * 8;
    for (int k0 = 0; k0 < K; k0 += 32) {
        glds16(A + (long long)(mb + srow) * lda + k0 + skq, As + wbase);
        glds16(B + (long long)(nb + srow) * ldb + k0 + skq, Bs + wbase);
        __syncthreads();
        half8 b0 = *(const half8*)&Bs[(wc * 32 +  0 + r) * 32 + qsw];
        half8 b1 = *(const half8*)&Bs[(wc * 32 + 16 + r) * 32 + qsw];
#pragma unroll
        for (int mi = 0; mi < 2; mi++) {
            half8 afr = *(const half8*)&As[(wr * 32 + mi * 16 + r) * 32 + qsw];
            acc[mi][0] = __builtin_amdgcn_mfma_f32_16x16x32_f16(afr, b0, acc[mi][0], 0, 0, 0);
            acc[mi][1] = __builtin_amdgcn_mfma_f32_16x16x32_f16(afr, b1, acc[mi][1], 0, 0, 0);
        }
        __syncthreads();
    }
#pragma unroll
    for (int mi = 0; mi < 2; mi++)
#pragma unroll
        for (int ni = 0; ni < 2; ni++) {
            int row0 = mb + wr * 32 + mi * 16 + quad * 4;
            int col = nb + wc * 32 + ni * 16 + r;
#pragma unroll
            for (int rr = 0; rr < 4; rr++)
                C[(long long)(row0 + rr) * ldc + col] = acc[mi][ni][rr];
        }
}

// ---------------------------------------------------------------------------
extern "C" void kernel_launch(void* const* d_in, const int* in_sizes, int n_in,
                              void* d_out, int out_size, void* d_ws, size_t ws_size,
                              hipStream_t stream) {
    (void)in_sizes; (void)n_in; (void)out_size; (void)ws_size;
    const int* idx = (const int*)d_in[0];
    float* out = (float*)d_out;

    char* ws = (char*)d_ws;
    float*  v32  = (float*) (ws);                   //   8 MiB [8192][256]
    half_t* vf   = (half_t*)(ws + (  8ll << 20));   //   4
    half_t* qf   = (half_t*)(ws + ( 12ll << 20));   //   4
    half_t* vT   = (half_t*)(ws + ( 16ll << 20));   //   4 [256][8192]
    half_t* lnf  = (half_t*)(ws + ( 20ll << 20));   //   4
    half_t* E    = (half_t*)(ws + ( 24ll << 20));   //  32 [4][2048][2048] f16
    float*  Pa   = (float*) (ws + ( 56ll << 20));   //  32 [16][2048][256] f32
    float*  Pu   = (float*) (ws + ( 88ll << 20));   //  64 [8][8192][256] f32
    half_t* dxT  = (half_t*)(ws + (216ll << 20));   //   4 [Nk][D]
    half_t* dyT  = (half_t*)(ws + (220ll << 20));   //   4
    half_t* eT   = (half_t*)(ws + (224ll << 20));   //   4 [256][8192]
    half_t* roT  = (half_t*)(ws + (228ll << 20));   // 128 KiB [256][256]
    int*    flag = (int*)   (ws + (228ll << 20) + (256ll << 10));
    // total ~229 MiB (ws 256 MiB)

    sniff_kernel<<<1, 256, 0, stream>>>((const unsigned short*)d_in[1], flag);
    tr_cvt16_kernel<<<dim3(MHk / 32, Dk / 32, 4), 256, 0, stream>>>(
        d_in[3], flag, dxT, Dk, MHk, (long long)Dk * MHk, (long long)Dk * MHk);
    tr_cvt16_kernel<<<dim3(MHk / 32, Dk / 32, 4), 256, 0, stream>>>(
        d_in[4], flag, dyT, Dk, MHk, (long long)Dk * MHk, (long long)Dk * MHk);
    tr_cvt16_kernel<<<dim3(Dk / 32, Nk / 32, 1), 256, 0, stream>>>(
        d_in[2], flag, eT, Nk, Dk, 0, 0);
    tr_cvt16_kernel<<<dim3(Dk / 32, Dk / 32, 1), 256, 0, stream>>>(
        d_in[5], flag, roT, Dk, Dk, 0, 0);

    embed_ln_kernel<<<BTk, 256, 0, stream>>>(idx, d_in[1], flag, v32, vf);

    for (int l = 0; l < LAYERS; l++) {
        rope_kernel<<<BTk, 128, 0, stream>>>(v32, qf);
        trv_kernel<<<dim3(Dk / 32, BTk / 32), 256, 0, stream>>>(v32, vT);
        // E[b] = tril(Qr Qr^T), fp16, all 4 batches (upper blocks skipped)
        gemm128e<<<dim3(Tk / 128, Tk / 128, 4), 256, 0, stream>>>(qf, E);
        // Pa[b*4+c] = E_chunk @ v (partials; dead causal chunks skipped)
        gemm128a<<<dim3(Dk / 128, Tk / 128, 16), 256, 0, stream>>>(E, vT, Pa);
        // lnf = LN(sum of alive partials)
        ln_rows_kernel<<<BTk, 256, 0, stream>>>(Pa, lnf);
        // fused decoder: y stays in LDS; Pu[8] partials
        fused_du<<<dim3(8, BTk / 128), 512, 0, stream>>>(
            vf, lnf, dxT, dyT, eT, Pu);
        // v += LN(sum of 8 partials)
        add_ln_kernel<<<BTk, 256, 0, stream>>>(Pu, v32, vf);
    }
    // logits = vf @ roT^T -> fp32 out
    gemm64h<<<dim3(Dk / 64, BTk / 64), 256, 0, stream>>>(
        vf, Dk, roT, Dk, out, Dk, Dk);
}

// Round 14
// 1367.765 us; speedup vs baseline: 1.2102x; 1.2102x over previous
//
#include <hip/hip_runtime.h>
#include <hip/hip_bf16.h>

typedef __hip_bfloat16 bf16;
typedef _Float16 half_t;
typedef __attribute__((ext_vector_type(8))) _Float16 half8;
typedef __attribute__((ext_vector_type(4))) float f32x4;

#define LN_EPS 1e-5f

static constexpr int Dk     = 256;   // model dim
static constexpr int Tk     = 2048;  // seq len
static constexpr int BTk    = 8192;  // B*T
static constexpr int MHk    = 2048;  // N/H
static constexpr int Nk     = 8192;  // hidden
static constexpr int LAYERS = 6;
static constexpr long long TD  = (long long)Tk * Dk;    // 524288
static constexpr long long BTD = (long long)BTk * Dk;   // 2097152
static constexpr long long TT  = (long long)Tk * Tk;    // 4194304

// LDS k-octet XOR swizzle (verified r10/r11: SQ_LDS_BANK_CONFLICT -> 0).
#define SKQ(t) ((((t) & 3) ^ (((t) >> 3) & 3)) * 8)

// ---------------------------------------------------------------------------
__device__ __forceinline__ float wave_reduce(float v) {
#pragma unroll
    for (int o = 32; o > 0; o >>= 1) v += __shfl_down(v, o);
    return v;
}

__device__ __forceinline__ float block_sum_256(float x, float* sbuf) {
    float s = wave_reduce(x);
    int lane = threadIdx.x & 63, wv = threadIdx.x >> 6;
    if (lane == 0) sbuf[wv] = s;
    __syncthreads();
    float r = sbuf[0] + sbuf[1] + sbuf[2] + sbuf[3];
    __syncthreads();
    return r;
}

__device__ __forceinline__ void glds16(const void* g, void* lds) {
    __builtin_amdgcn_global_load_lds(
        (const __attribute__((address_space(1))) void*)g,
        (__attribute__((address_space(3))) void*)lds, 16, 0, 0);
}

// rope for one row t: thread i<128 handles dims (i, i+128) of nv[256] in LDS
__device__ __forceinline__ void rope_row(const float* nv, int t, half_t* qrow) {
    int i = threadIdx.x;
    if (i < 128) {
        float invf = powf(10000.f, -(float)i / 128.f);
        float ang = (float)t * invf;
        float s, c;
        sincosf(ang, &s, &c);
        float q1 = nv[i], q2 = nv[128 + i];
        qrow[i]       = (half_t)(q1 * c - q2 * s);
        qrow[128 + i] = (half_t)(q2 * c + q1 * s);
    }
}

// ---------------------------------------------------------------------------
// input dtype sniffer (insurance; inputs confirmed fp32)
__global__ __launch_bounds__(256) void sniff_kernel(const unsigned short* __restrict__ w,
                                                    int* __restrict__ flag) {
    __shared__ float sbuf[4];
    int tid = threadIdx.x;
    float cnt = 0.f;
    for (int i = tid; i < 1024; i += 256) {
        int e = (w[i] >> 7) & 0xFF;
        if (e >= 128) cnt += 1.f;
    }
    float tot = block_sum_256(cnt, sbuf);
    if (tid == 0) *flag = (tot > 32.f) ? 1 : 0;
}

// transpose + fp16 convert: src [R][C] (per z) -> dst [C][R] fp16
__global__ __launch_bounds__(256) void tr_cvt16_kernel(const void* __restrict__ src,
                                                       const int* __restrict__ flag,
                                                       half_t* __restrict__ dst,
                                                       int R, int C,
                                                       long long sz, long long dz) {
    __shared__ float t[32][33];
    bool f32 = (*flag != 0);
    int ct = blockIdx.x * 32, rt = blockIdx.y * 32;
    long long so = (long long)blockIdx.z * sz, dofs = (long long)blockIdx.z * dz;
    int tx = threadIdx.x & 31, ty = threadIdx.x >> 5;
#pragma unroll
    for (int i = 0; i < 4; i++) {
        long long idx = so + (long long)(rt + ty + i * 8) * C + ct + tx;
        t[ty + i * 8][tx] = f32 ? ((const float*)src)[idx] : (float)((const bf16*)src)[idx];
    }
    __syncthreads();
#pragma unroll
    for (int i = 0; i < 4; i++) {
        long long odx = dofs + (long long)(ct + ty + i * 8) * R + rt + tx;
        dst[odx] = (half_t)t[tx][ty + i * 8];
    }
}

// v32 [BT][D] fp32 -> vT [D][BT] fp16
__global__ __launch_bounds__(256) void trv_kernel(const float* __restrict__ src,
                                                  half_t* __restrict__ dst) {
    __shared__ float t[32][33];
    int ct = blockIdx.x * 32, rt = blockIdx.y * 32;
    int tx = threadIdx.x & 31, ty = threadIdx.x >> 5;
#pragma unroll
    for (int i = 0; i < 4; i++)
        t[ty + i * 8][tx] = src[(long long)(rt + ty + i * 8) * Dk + ct + tx];
    __syncthreads();
#pragma unroll
    for (int i = 0; i < 4; i++)
        dst[(long long)(ct + ty + i * 8) * BTk + rt + tx] = (half_t)t[tx][ty + i * 8];
}

// ---------------------------------------------------------------------------
// v = layernorm(wte[idx]) -> v32 fp32, vf fp16, qf fp16 (rope fused)
__global__ __launch_bounds__(256) void embed_ln_kernel(const int* __restrict__ idx,
                                                       const void* __restrict__ wte,
                                                       const int* __restrict__ flag,
                                                       float* __restrict__ v,
                                                       half_t* __restrict__ vf,
                                                       half_t* __restrict__ qf) {
    __shared__ float sbuf[4];
    __shared__ float nvs[256];
    int bt = blockIdx.x, tid = threadIdx.x;
    int id = idx[bt];
    bool f32 = (*flag != 0);
    float x = f32 ? ((const float*)wte)[id * Dk + tid]
                  : (float)((const bf16*)wte)[id * Dk + tid];
    float mu = block_sum_256(x, sbuf) * (1.f / 256.f);
    float d = x - mu;
    float var = block_sum_256(d * d, sbuf) * (1.f / 256.f);
    float r = d * rsqrtf(var + LN_EPS);
    v[bt * Dk + tid] = r;
    vf[bt * Dk + tid] = (half_t)r;
    nvs[tid] = r;
    __syncthreads();
    rope_row(nvs, bt & (Tk - 1), qf + (long long)bt * Dk);
}

// lnf = fp16(layernorm(sum of alive a-partials)).
__global__ __launch_bounds__(256) void ln_rows_kernel(const float* __restrict__ Pa,
                                                      half_t* __restrict__ of) {
    __shared__ float sbuf[4];
    int bt = blockIdx.x, tid = threadIdx.x;
    int b = bt >> 11, t = bt & (Tk - 1);
    int ncnt = ((t & ~127) >> 9) + 1;
    const float* p = Pa + ((long long)(b << 2)) * TD + (long long)t * Dk + tid;
    float x = 0.f;
    for (int c = 0; c < ncnt; c++) x += p[(long long)c * TD];
    float mu = block_sum_256(x, sbuf) * (1.f / 256.f);
    float d = x - mu;
    float var = block_sum_256(d * d, sbuf) * (1.f / 256.f);
    float r = d * rsqrtf(var + LN_EPS);
    of[bt * Dk + tid] = (half_t)r;
}

// v += layernorm(sum of 4 update-partials) -> v32, vf, qf (rope fused)
__global__ __launch_bounds__(256) void add_ln_kernel(const float* __restrict__ Pu,
                                                     float* __restrict__ v,
                                                     half_t* __restrict__ vf,
                                                     half_t* __restrict__ qf) {
    __shared__ float sbuf[4];
    __shared__ float nvs[256];
    int bt = blockIdx.x, tid = threadIdx.x;
    long long e = (long long)bt * Dk + tid;
    float x = Pu[e] + Pu[e + BTD] + Pu[e + 2 * BTD] + Pu[e + 3 * BTD];
    float mu = block_sum_256(x, sbuf) * (1.f / 256.f);
    float d = x - mu;
    float var = block_sum_256(d * d, sbuf) * (1.f / 256.f);
    float r = d * rsqrtf(var + LN_EPS);
    float nv = v[e] + r;
    v[e] = nv;
    vf[e] = (half_t)nv;
    nvs[tid] = nv;
    __syncthreads();
    rope_row(nvs, bt & (Tk - 1), qf + (long long)bt * Dk);
}

// ---------------------------------------------------------------------------
// Energy: E[b] = tril(Qr Qr^T), fp16, 128x128 swizzled, z = batch.
// Upper blocks never read downstream -> early exit.
__global__ __launch_bounds__(256) void gemm128e(
    const half_t* __restrict__ Q, half_t* __restrict__ E) {
    __shared__ __align__(16) half_t As[128 * 32];
    __shared__ __align__(16) half_t Bs[128 * 32];
    const int tid = threadIdx.x;
    const int lane = tid & 63, wv = tid >> 6;
    const int wr = wv >> 1, wc = wv & 1;
    const int quad = lane >> 4, r = lane & 15;
    const int qsw = (quad ^ ((r >> 1) & 3)) * 8;
    const int mb = blockIdx.y * 128, nb = blockIdx.x * 128;
    if ((int)blockIdx.x > (int)blockIdx.y) return;   // never read
    const half_t* Qb = Q + (long long)blockIdx.z * TD;
    half_t* Eb = E + (long long)blockIdx.z * TT;

    f32x4 acc[4][4] = {};
    const int srow = tid >> 2, skq = SKQ(tid);
    const int wbase = (tid & 192) * 8;
    for (int k0 = 0; k0 < Dk; k0 += 32) {
#pragma unroll
        for (int rnd = 0; rnd < 2; rnd++) {
            int row = rnd * 64 + srow;
            glds16(Qb + (long long)(mb + row) * Dk + k0 + skq, As + rnd * 2048 + wbase);
            glds16(Qb + (long long)(nb + row) * Dk + k0 + skq, Bs + rnd * 2048 + wbase);
        }
        __syncthreads();
        half8 bfr[4];
#pragma unroll
        for (int ni = 0; ni < 4; ni++)
            bfr[ni] = *(const half8*)&Bs[(wc * 64 + ni * 16 + r) * 32 + qsw];
#pragma unroll
        for (int mi = 0; mi < 4; mi++) {
            half8 afr = *(const half8*)&As[(wr * 64 + mi * 16 + r) * 32 + qsw];
#pragma unroll
            for (int ni = 0; ni < 4; ni++)
                acc[mi][ni] = __builtin_amdgcn_mfma_f32_16x16x32_f16(afr, bfr[ni], acc[mi][ni], 0, 0, 0);
        }
        __syncthreads();
    }
#pragma unroll
    for (int mi = 0; mi < 4; mi++)
#pragma unroll
        for (int ni = 0; ni < 4; ni++) {
            int row0 = mb + wr * 64 + mi * 16 + quad * 4;
            int col = nb + wc * 64 + ni * 16 + r;
#pragma unroll
            for (int rr = 0; rr < 4; rr++) {
                int row = row0 + rr;
                float val = (row < col) ? 0.f : acc[mi][ni][rr];
                Eb[(long long)row * Tk + col] = (half_t)val;
            }
        }
}

// ---------------------------------------------------------------------------
// a-GEMM: Pa[z] = E_chunk @ V, 128x128 swizzled, split-K partial stores.
// GRID SWAPPED (r14): x = m-tile (16), y = n-tile (2) so the 2 blocks sharing
// an E-row-panel are 16 ids apart -> same XCD -> E fetched once.
__global__ __launch_bounds__(256) void gemm128a(
    const half_t* __restrict__ E, const half_t* __restrict__ vT,
    float* __restrict__ Pa) {
    __shared__ __align__(16) half_t As[128 * 32];
    __shared__ __align__(16) half_t Bs[128 * 32];
    const int tid = threadIdx.x;
    const int lane = tid & 63, wv = tid >> 6;
    const int wr = wv >> 1, wc = wv & 1;
    const int quad = lane >> 4, r = lane & 15;
    const int qsw = (quad ^ ((r >> 1) & 3)) * 8;
    const int mb = blockIdx.x * 128, nb = blockIdx.y * 128;   // swapped
    const int b = blockIdx.z >> 2, c = blockIdx.z & 3;
    const int kbeg = c * 512;
    const int kend = min(mb + 128, kbeg + 512);
    if (kend <= kbeg) return;

    const half_t* Ab = E + (long long)b * TT;
    const half_t* Bb = vT + (long long)b * Tk;
    float* Pc = Pa + (long long)blockIdx.z * TD;
    f32x4 acc[4][4] = {};
    const int srow = tid >> 2, skq = SKQ(tid);
    const int wbase = (tid & 192) * 8;
    for (int k0 = kbeg; k0 < kend; k0 += 32) {
#pragma unroll
        for (int rnd = 0; rnd < 2; rnd++) {
            int row = rnd * 64 + srow;
            glds16(Ab + (long long)(mb + row) * Tk + k0 + skq, As + rnd * 2048 + wbase);
            glds16(Bb + (long long)(nb + row) * BTk + k0 + skq, Bs + rnd * 2048 + wbase);
        }
        __syncthreads();
        half8 bfr[4];
#pragma unroll
        for (int ni = 0; ni < 4; ni++)
            bfr[ni] = *(const half8*)&Bs[(wc * 64 + ni * 16 + r) * 32 + qsw];
#pragma unroll
        for (int mi = 0; mi < 4; mi++) {
            half8 afr = *(const half8*)&As[(wr * 64 + mi * 16 + r) * 32 + qsw];
#pragma unroll
            for (int ni = 0; ni < 4; ni++)
                acc[mi][ni] = __builtin_amdgcn_mfma_f32_16x16x32_f16(afr, bfr[ni], acc[mi][ni], 0, 0, 0);
        }
        __syncthreads();
    }
#pragma unroll
    for (int mi = 0; mi < 4; mi++)
#pragma unroll
        for (int ni = 0; ni < 4; ni++) {
            int row0 = mb + wr * 64 + mi * 16 + quad * 4;
            int col = nb + wc * 64 + ni * 16 + r;
#pragma unroll
            for (int rr = 0; rr < 4; rr++)
                Pc[(long long)(row0 + rr) * Dk + col] = acc[mi][ni][rr];
        }
}

// ---------------------------------------------------------------------------
// Fused dual fp16 GEMM, 512 thr, 128x128 tile, swizzled.
// XCD REMAP (r14): flat id -> xcd = id&7 arranged 2(m-groups)x4(n-groups);
// within XCD, m-major so the (n,h) weight slab (2 MB) stays L2-resident.
// Per XCD: A 4 MB + B 2 MB -> predicted fetch ~48 MB vs 72.
__global__ __launch_bounds__(512) void dual_gemm(
    const half_t* __restrict__ A1,   // vf  [BT][D]
    const half_t* __restrict__ A2,   // lnf [BT][D]
    const half_t* __restrict__ dxT,  // [Nk][D]
    const half_t* __restrict__ dyT,  // [Nk][D]
    half_t* __restrict__ C) {        // y16 [BT][Nk]
    __shared__ __align__(16) half_t As1[4096];
    __shared__ __align__(16) half_t As2[4096];
    __shared__ __align__(16) half_t Bs1[4096];
    __shared__ __align__(16) half_t Bs2[4096];
    const int tid = threadIdx.x;
    const int lane = tid & 63, wv = tid >> 6;     // 8 waves
    const int wr = wv >> 2, wc = wv & 3;          // 2 x 4 wave grid
    const int quad = lane >> 4, r = lane & 15;
    const int qsw = (quad ^ ((r >> 1) & 3)) * 8;
    // block remap: grid (16,64,4) flat -> (m,n,h)
    const int flat = blockIdx.x + 16 * (blockIdx.y + 64 * blockIdx.z);
    const int xcd = flat & 7, j = flat >> 3;
    const int mt = (xcd >> 2) * 32 + (j >> 4);          // 0..63
    const int nt = (xcd & 3) * 4 + (j & 3);             // 0..15
    const int h  = (j >> 2) & 3;                        // 0..3
    const int mb = mt * 128, nb = nt * 128;
    const half_t* B1 = dxT + (long long)h * MHk * Dk;
    const half_t* B2 = dyT + (long long)h * MHk * Dk;

    f32x4 accX[4][2] = {};
    f32x4 accY[4][2] = {};
    const int srow = tid >> 2, skq = SKQ(tid);
    const int wbase = (tid & 448) * 8;
    for (int k0 = 0; k0 < Dk; k0 += 32) {
        glds16(A1 + (long long)(mb + srow) * Dk + k0 + skq, As1 + wbase);
        glds16(A2 + (long long)(mb + srow) * Dk + k0 + skq, As2 + wbase);
        glds16(B1 + (long long)(nb + srow) * Dk + k0 + skq, Bs1 + wbase);
        glds16(B2 + (long long)(nb + srow) * Dk + k0 + skq, Bs2 + wbase);
        __syncthreads();
        half8 b1f[2], b2f[2];
#pragma unroll
        for (int ni = 0; ni < 2; ni++) {
            b1f[ni] = *(const half8*)&Bs1[(wc * 32 + ni * 16 + r) * 32 + qsw];
            b2f[ni] = *(const half8*)&Bs2[(wc * 32 + ni * 16 + r) * 32 + qsw];
        }
#pragma unroll
        for (int mi = 0; mi < 4; mi++) {
            half8 a1 = *(const half8*)&As1[(wr * 64 + mi * 16 + r) * 32 + qsw];
            half8 a2 = *(const half8*)&As2[(wr * 64 + mi * 16 + r) * 32 + qsw];
#pragma unroll
            for (int ni = 0; ni < 2; ni++) {
                accX[mi][ni] = __builtin_amdgcn_mfma_f32_16x16x32_f16(a1, b1f[ni], accX[mi][ni], 0, 0, 0);
                accY[mi][ni] = __builtin_amdgcn_mfma_f32_16x16x32_f16(a2, b2f[ni], accY[mi][ni], 0, 0, 0);
            }
        }
        __syncthreads();
    }
#pragma unroll
    for (int mi = 0; mi < 4; mi++)
#pragma unroll
        for (int ni = 0; ni < 2; ni++) {
            int row0 = mb + wr * 64 + mi * 16 + quad * 4;
            int col = h * MHk + nb + wc * 32 + ni * 16 + r;
#pragma unroll
            for (int rr = 0; rr < 4; rr++) {
                float val = fmaxf(accY[mi][ni][rr], 0.f) * fmaxf(accX[mi][ni][rr], 0.f);
                C[(long long)(row0 + rr) * Nk + col] = (half_t)val;
            }
        }
}

// ---------------------------------------------------------------------------
// Update: Pu[z] = y @ enc over K-chunk z*2048, 128x128 swizzled, partials.
// GRID SWAPPED (r14): x = m-tile (64), y = n-tile (2) so the 2 blocks
// sharing a y16 row-panel are 64 ids apart -> same XCD -> y16 fetched once.
__global__ __launch_bounds__(256) void gemm128u(
    const half_t* __restrict__ A, const half_t* __restrict__ B,
    float* __restrict__ Pu) {
    __shared__ __align__(16) half_t As[128 * 32];
    __shared__ __align__(16) half_t Bs[128 * 32];
    const int tid = threadIdx.x;
    const int lane = tid & 63, wv = tid >> 6;
    const int wr = wv >> 1, wc = wv & 1;
    const int quad = lane >> 4, r = lane & 15;
    const int qsw = (quad ^ ((r >> 1) & 3)) * 8;
    const int mb = blockIdx.x * 128, nb = blockIdx.y * 128;   // swapped
    const int kbeg = blockIdx.z * 2048;
    float* Pc = Pu + (long long)blockIdx.z * BTD;

    f32x4 acc[4][4] = {};
    const int srow = tid >> 2, skq = SKQ(tid);
    const int wbase = (tid & 192) * 8;
    for (int k0 = kbeg; k0 < kbeg + 2048; k0 += 32) {
#pragma unroll
        for (int rnd = 0; rnd < 2; rnd++) {
            int row = rnd * 64 + srow;
            glds16(A + (long long)(mb + row) * Nk + k0 + skq, As + rnd * 2048 + wbase);
            glds16(B + (long long)(nb + row) * Nk + k0 + skq, Bs + rnd * 2048 + wbase);
        }
        __syncthreads();
        half8 bfr[4];
#pragma unroll
        for (int ni = 0; ni < 4; ni++)
            bfr[ni] = *(const half8*)&Bs[(wc * 64 + ni * 16 + r) * 32 + qsw];
#pragma unroll
        for (int mi = 0; mi < 4; mi++) {
            half8 afr = *(const half8*)&As[(wr * 64 + mi * 16 + r) * 32 + qsw];
#pragma unroll
            for (int ni = 0; ni < 4; ni++)
                acc[mi][ni] = __builtin_amdgcn_mfma_f32_16x16x32_f16(afr, bfr[ni], acc[mi][ni], 0, 0, 0);
        }
        __syncthreads();
    }
#pragma unroll
    for (int mi = 0; mi < 4; mi++)
#pragma unroll
        for (int ni = 0; ni < 4; ni++) {
            int row0 = mb + wr * 64 + mi * 16 + quad * 4;
            int col = nb + wc * 64 + ni * 16 + r;
#pragma unroll
            for (int rr = 0; rr < 4; rr++)
                Pc[(long long)(row0 + rr) * Dk + col] = acc[mi][ni][rr];
        }
}

// ---------------------------------------------------------------------------
// Plain fp16 64x64 async GEMM, swizzled, fp32 store — readout.
__global__ __launch_bounds__(256) void gemm64h(
    const half_t* __restrict__ A, int lda,
    const half_t* __restrict__ B, int ldb,
    float* __restrict__ C, int ldc, int K) {
    __shared__ __align__(16) half_t As[64 * 32];
    __shared__ __align__(16) half_t Bs[64 * 32];
    const int tid = threadIdx.x;
    const int lane = tid & 63, wv = tid >> 6;
    const int wr = wv >> 1, wc = wv & 1;
    const int quad = lane >> 4, r = lane & 15;
    const int qsw = (quad ^ ((r >> 1) & 3)) * 8;
    const int mb = blockIdx.y * 64, nb = blockIdx.x * 64;

    f32x4 acc[2][2] = {};
    const int srow = tid >> 2, skq = SKQ(tid);
    const int wbase = (tid & 192) * 8;
    for (int k0 = 0; k0 < K; k0 += 32) {
        glds16(A + (long long)(mb + srow) * lda + k0 + skq, As + wbase);
        glds16(B + (long long)(nb + srow) * ldb + k0 + skq, Bs + wbase);
        __syncthreads();
        half8 b0 = *(const half8*)&Bs[(wc * 32 +  0 + r) * 32 + qsw];
        half8 b1 = *(const half8*)&Bs[(wc * 32 + 16 + r) * 32 + qsw];
#pragma unroll
        for (int mi = 0; mi < 2; mi++) {
            half8 afr = *(const half8*)&As[(wr * 32 + mi * 16 + r) * 32 + qsw];
            acc[mi][0] = __builtin_amdgcn_mfma_f32_16x16x32_f16(afr, b0, acc[mi][0], 0, 0, 0);
            acc[mi][1] = __builtin_amdgcn_mfma_f32_16x16x32_f16(afr, b1, acc[mi][1], 0, 0, 0);
        }
        __syncthreads();
    }
#pragma unroll
    for (int mi = 0; mi < 2; mi++)
#pragma unroll
        for (int ni = 0; ni < 2; ni++) {
            int row0 = mb + wr * 32 + mi * 16 + quad * 4;
            int col = nb + wc * 32 + ni * 16 + r;
#pragma unroll
            for (int rr = 0; rr < 4; rr++)
                C[(long long)(row0 + rr) * ldc + col] = acc[mi][ni][rr];
        }
}

// ---------------------------------------------------------------------------
extern "C" void kernel_launch(void* const* d_in, const int* in_sizes, int n_in,
                              void* d_out, int out_size, void* d_ws, size_t ws_size,
                              hipStream_t stream) {
    (void)in_sizes; (void)n_in; (void)out_size; (void)ws_size;
    const int* idx = (const int*)d_in[0];
    float* out = (float*)d_out;

    char* ws = (char*)d_ws;
    float*  v32  = (float*) (ws);                   //   8 MiB [8192][256]
    half_t* vf   = (half_t*)(ws + (  8ll << 20));   //   4
    half_t* qf   = (half_t*)(ws + ( 12ll << 20));   //   4
    half_t* vT   = (half_t*)(ws + ( 16ll << 20));   //   4 [256][8192]
    half_t* lnf  = (half_t*)(ws + ( 20ll << 20));   //   4
    half_t* E    = (half_t*)(ws + ( 24ll << 20));   //  32 [4][2048][2048] f16
    float*  Pa   = (float*) (ws + ( 56ll << 20));   //  32 [16][2048][256] f32
    float*  Pu   = (float*) (ws + ( 24ll << 20));   //  64 [4][8192][256] f32 (aliases E+Pa, phase-disjoint)
    half_t* y16  = (half_t*)(ws + ( 88ll << 20));   // 128 [8192][8192] f16
    half_t* dxT  = (half_t*)(ws + (216ll << 20));   //   4 [Nk][D]
    half_t* dyT  = (half_t*)(ws + (220ll << 20));   //   4
    half_t* eT   = (half_t*)(ws + (224ll << 20));   //   4 [256][8192]
    half_t* roT  = (half_t*)(ws + (228ll << 20));   // 128 KiB [256][256]
    int*    flag = (int*)   (ws + (228ll << 20) + (256ll << 10));
    // total ~229 MiB (ws 256 MiB)

    sniff_kernel<<<1, 256, 0, stream>>>((const unsigned short*)d_in[1], flag);
    tr_cvt16_kernel<<<dim3(MHk / 32, Dk / 32, 4), 256, 0, stream>>>(
        d_in[3], flag, dxT, Dk, MHk, (long long)Dk * MHk, (long long)Dk * MHk);
    tr_cvt16_kernel<<<dim3(MHk / 32, Dk / 32, 4), 256, 0, stream>>>(
        d_in[4], flag, dyT, Dk, MHk, (long long)Dk * MHk, (long long)Dk * MHk);
    tr_cvt16_kernel<<<dim3(Dk / 32, Nk / 32, 1), 256, 0, stream>>>(
        d_in[2], flag, eT, Nk, Dk, 0, 0);
    tr_cvt16_kernel<<<dim3(Dk / 32, Dk / 32, 1), 256, 0, stream>>>(
        d_in[5], flag, roT, Dk, Dk, 0, 0);

    embed_ln_kernel<<<BTk, 256, 0, stream>>>(idx, d_in[1], flag, v32, vf, qf);

    for (int l = 0; l < LAYERS; l++) {
        trv_kernel<<<dim3(Dk / 32, BTk / 32), 256, 0, stream>>>(v32, vT);
        // E[b] = tril(Qr Qr^T), fp16, all 4 batches (upper blocks skipped)
        gemm128e<<<dim3(Tk / 128, Tk / 128, 4), 256, 0, stream>>>(qf, E);
        // Pa[b*4+c] = E_chunk @ v (partials; dead causal chunks skipped)
        gemm128a<<<dim3(Tk / 128, Dk / 128, 16), 256, 0, stream>>>(E, vT, Pa);
        // lnf = LN(sum of alive partials)
        ln_rows_kernel<<<BTk, 256, 0, stream>>>(Pa, lnf);
        // y (all 4 heads, one dispatch, XCD-remapped)
        dual_gemm<<<dim3(MHk / 128, BTk / 128, 4), 512, 0, stream>>>(
            vf, lnf, dxT, dyT, y16);
        // Pu[z] = y @ enc, K-chunk 2048 (partials; A-locality grid)
        gemm128u<<<dim3(BTk / 128, Dk / 128, 4), 256, 0, stream>>>(y16, eT, Pu);
        // v += LN(sum of partials); rope fused -> qf for next layer
        add_ln_kernel<<<BTk, 256, 0, stream>>>(Pu, v32, vf, qf);
    }
    // logits = vf @ roT^T -> fp32 out
    gemm64h<<<dim3(Dk / 64, BTk / 64), 256, 0, stream>>>(
        vf, Dk, roT, Dk, out, Dk, Dk);
}

// Round 15
// 1268.548 us; speedup vs baseline: 1.3048x; 1.0782x over previous
//
#include <hip/hip_runtime.h>
#include <hip/hip_bf16.h>

typedef __hip_bfloat16 bf16;
typedef _Float16 half_t;
typedef __attribute__((ext_vector_type(8))) _Float16 half8;
typedef __attribute__((ext_vector_type(4))) float f32x4;

#define LN_EPS 1e-5f

static constexpr int Dk     = 256;   // model dim
static constexpr int Tk     = 2048;  // seq len
static constexpr int BTk    = 8192;  // B*T
static constexpr int MHk    = 2048;  // N/H
static constexpr int Nk     = 8192;  // hidden
static constexpr int LAYERS = 6;
static constexpr long long TD  = (long long)Tk * Dk;    // 524288
static constexpr long long BTD = (long long)BTk * Dk;   // 2097152
static constexpr long long TT  = (long long)Tk * Tk;    // 4194304

// LDS k-octet XOR swizzle (verified r10/r11: SQ_LDS_BANK_CONFLICT -> 0).
#define SKQ(t) ((((t) & 3) ^ (((t) >> 3) & 3)) * 8)

// ---------------------------------------------------------------------------
__device__ __forceinline__ float wave_reduce(float v) {
#pragma unroll
    for (int o = 32; o > 0; o >>= 1) v += __shfl_down(v, o);
    return v;
}

__device__ __forceinline__ float block_sum_256(float x, float* sbuf) {
    float s = wave_reduce(x);
    int lane = threadIdx.x & 63, wv = threadIdx.x >> 6;
    if (lane == 0) sbuf[wv] = s;
    __syncthreads();
    float r = sbuf[0] + sbuf[1] + sbuf[2] + sbuf[3];
    __syncthreads();
    return r;
}

__device__ __forceinline__ void glds16(const void* g, void* lds) {
    __builtin_amdgcn_global_load_lds(
        (const __attribute__((address_space(1))) void*)g,
        (__attribute__((address_space(3))) void*)lds, 16, 0, 0);
}

// rope for one row t: thread i<128 handles dims (i, i+128) of nv[256] in LDS
__device__ __forceinline__ void rope_row(const float* nv, int t, half_t* qrow) {
    int i = threadIdx.x;
    if (i < 128) {
        float invf = powf(10000.f, -(float)i / 128.f);
        float ang = (float)t * invf;
        float s, c;
        sincosf(ang, &s, &c);
        float q1 = nv[i], q2 = nv[128 + i];
        qrow[i]       = (half_t)(q1 * c - q2 * s);
        qrow[128 + i] = (half_t)(q2 * c + q1 * s);
    }
}

// ---------------------------------------------------------------------------
// input dtype sniffer (insurance; inputs confirmed fp32)
__global__ __launch_bounds__(256) void sniff_kernel(const unsigned short* __restrict__ w,
                                                    int* __restrict__ flag) {
    __shared__ float sbuf[4];
    int tid = threadIdx.x;
    float cnt = 0.f;
    for (int i = tid; i < 1024; i += 256) {
        int e = (w[i] >> 7) & 0xFF;
        if (e >= 128) cnt += 1.f;
    }
    float tot = block_sum_256(cnt, sbuf);
    if (tid == 0) *flag = (tot > 32.f) ? 1 : 0;
}

// transpose + fp16 convert: src [R][C] (per z) -> dst [C][R] fp16
__global__ __launch_bounds__(256) void tr_cvt16_kernel(const void* __restrict__ src,
                                                       const int* __restrict__ flag,
                                                       half_t* __restrict__ dst,
                                                       int R, int C,
                                                       long long sz, long long dz) {
    __shared__ float t[32][33];
    bool f32 = (*flag != 0);
    int ct = blockIdx.x * 32, rt = blockIdx.y * 32;
    long long so = (long long)blockIdx.z * sz, dofs = (long long)blockIdx.z * dz;
    int tx = threadIdx.x & 31, ty = threadIdx.x >> 5;
#pragma unroll
    for (int i = 0; i < 4; i++) {
        long long idx = so + (long long)(rt + ty + i * 8) * C + ct + tx;
        t[ty + i * 8][tx] = f32 ? ((const float*)src)[idx] : (float)((const bf16*)src)[idx];
    }
    __syncthreads();
#pragma unroll
    for (int i = 0; i < 4; i++) {
        long long odx = dofs + (long long)(ct + ty + i * 8) * R + rt + tx;
        dst[odx] = (half_t)t[tx][ty + i * 8];
    }
}

// v32 [BT][D] fp32 -> vT [D][BT] fp16
__global__ __launch_bounds__(256) void trv_kernel(const float* __restrict__ src,
                                                  half_t* __restrict__ dst) {
    __shared__ float t[32][33];
    int ct = blockIdx.x * 32, rt = blockIdx.y * 32;
    int tx = threadIdx.x & 31, ty = threadIdx.x >> 5;
#pragma unroll
    for (int i = 0; i < 4; i++)
        t[ty + i * 8][tx] = src[(long long)(rt + ty + i * 8) * Dk + ct + tx];
    __syncthreads();
#pragma unroll
    for (int i = 0; i < 4; i++)
        dst[(long long)(ct + ty + i * 8) * BTk + rt + tx] = (half_t)t[tx][ty + i * 8];
}

// ---------------------------------------------------------------------------
// v = layernorm(wte[idx]) -> v32 fp32, vf fp16, qf fp16 (rope fused)
__global__ __launch_bounds__(256) void embed_ln_kernel(const int* __restrict__ idx,
                                                       const void* __restrict__ wte,
                                                       const int* __restrict__ flag,
                                                       float* __restrict__ v,
                                                       half_t* __restrict__ vf,
                                                       half_t* __restrict__ qf) {
    __shared__ float sbuf[4];
    __shared__ float nvs[256];
    int bt = blockIdx.x, tid = threadIdx.x;
    int id = idx[bt];
    bool f32 = (*flag != 0);
    float x = f32 ? ((const float*)wte)[id * Dk + tid]
                  : (float)((const bf16*)wte)[id * Dk + tid];
    float mu = block_sum_256(x, sbuf) * (1.f / 256.f);
    float d = x - mu;
    float var = block_sum_256(d * d, sbuf) * (1.f / 256.f);
    float r = d * rsqrtf(var + LN_EPS);
    v[bt * Dk + tid] = r;
    vf[bt * Dk + tid] = (half_t)r;
    nvs[tid] = r;
    __syncthreads();
    rope_row(nvs, bt & (Tk - 1), qf + (long long)bt * Dk);
}

// lnf = fp16(layernorm(sum of alive a-partials)).
__global__ __launch_bounds__(256) void ln_rows_kernel(const float* __restrict__ Pa,
                                                      half_t* __restrict__ of) {
    __shared__ float sbuf[4];
    int bt = blockIdx.x, tid = threadIdx.x;
    int b = bt >> 11, t = bt & (Tk - 1);
    int ncnt = ((t & ~127) >> 9) + 1;
    const float* p = Pa + ((long long)(b << 2)) * TD + (long long)t * Dk + tid;
    float x = 0.f;
    for (int c = 0; c < ncnt; c++) x += p[(long long)c * TD];
    float mu = block_sum_256(x, sbuf) * (1.f / 256.f);
    float d = x - mu;
    float var = block_sum_256(d * d, sbuf) * (1.f / 256.f);
    float r = d * rsqrtf(var + LN_EPS);
    of[bt * Dk + tid] = (half_t)r;
}

// v += layernorm(sum of 4 update-partials) -> v32, vf, qf (rope fused)
__global__ __launch_bounds__(256) void add_ln_kernel(const float* __restrict__ Pu,
                                                     float* __restrict__ v,
                                                     half_t* __restrict__ vf,
                                                     half_t* __restrict__ qf) {
    __shared__ float sbuf[4];
    __shared__ float nvs[256];
    int bt = blockIdx.x, tid = threadIdx.x;
    long long e = (long long)bt * Dk + tid;
    float x = Pu[e] + Pu[e + BTD] + Pu[e + 2 * BTD] + Pu[e + 3 * BTD];
    float mu = block_sum_256(x, sbuf) * (1.f / 256.f);
    float d = x - mu;
    float var = block_sum_256(d * d, sbuf) * (1.f / 256.f);
    float r = d * rsqrtf(var + LN_EPS);
    float nv = v[e] + r;
    v[e] = nv;
    vf[e] = (half_t)nv;
    nvs[tid] = nv;
    __syncthreads();
    rope_row(nvs, bt & (Tk - 1), qf + (long long)bt * Dk);
}

// ---------------------------------------------------------------------------
// Energy: E[b] = tril(Qr Qr^T), fp16, 128x128 swizzled, z = batch.
__global__ __launch_bounds__(256) void gemm128e(
    const half_t* __restrict__ Q, half_t* __restrict__ E) {
    __shared__ __align__(16) half_t As[128 * 32];
    __shared__ __align__(16) half_t Bs[128 * 32];
    const int tid = threadIdx.x;
    const int lane = tid & 63, wv = tid >> 6;
    const int wr = wv >> 1, wc = wv & 1;
    const int quad = lane >> 4, r = lane & 15;
    const int qsw = (quad ^ ((r >> 1) & 3)) * 8;
    const int mb = blockIdx.y * 128, nb = blockIdx.x * 128;
    if ((int)blockIdx.x > (int)blockIdx.y) return;   // never read
    const half_t* Qb = Q + (long long)blockIdx.z * TD;
    half_t* Eb = E + (long long)blockIdx.z * TT;

    f32x4 acc[4][4] = {};
    const int srow = tid >> 2, skq = SKQ(tid);
    const int wbase = (tid & 192) * 8;
    for (int k0 = 0; k0 < Dk; k0 += 32) {
#pragma unroll
        for (int rnd = 0; rnd < 2; rnd++) {
            int row = rnd * 64 + srow;
            glds16(Qb + (long long)(mb + row) * Dk + k0 + skq, As + rnd * 2048 + wbase);
            glds16(Qb + (long long)(nb + row) * Dk + k0 + skq, Bs + rnd * 2048 + wbase);
        }
        __syncthreads();
        half8 bfr[4];
#pragma unroll
        for (int ni = 0; ni < 4; ni++)
            bfr[ni] = *(const half8*)&Bs[(wc * 64 + ni * 16 + r) * 32 + qsw];
#pragma unroll
        for (int mi = 0; mi < 4; mi++) {
            half8 afr = *(const half8*)&As[(wr * 64 + mi * 16 + r) * 32 + qsw];
#pragma unroll
            for (int ni = 0; ni < 4; ni++)
                acc[mi][ni] = __builtin_amdgcn_mfma_f32_16x16x32_f16(afr, bfr[ni], acc[mi][ni], 0, 0, 0);
        }
        __syncthreads();
    }
#pragma unroll
    for (int mi = 0; mi < 4; mi++)
#pragma unroll
        for (int ni = 0; ni < 4; ni++) {
            int row0 = mb + wr * 64 + mi * 16 + quad * 4;
            int col = nb + wc * 64 + ni * 16 + r;
#pragma unroll
            for (int rr = 0; rr < 4; rr++) {
                int row = row0 + rr;
                float val = (row < col) ? 0.f : acc[mi][ni][rr];
                Eb[(long long)row * Tk + col] = (half_t)val;
            }
        }
}

// ---------------------------------------------------------------------------
// a-GEMM: Pa[z] = E_chunk @ V, 128x128 swizzled, split-K partial stores.
// x = m-tile so blocks sharing an E-panel land on one XCD (r14 win).
__global__ __launch_bounds__(256) void gemm128a(
    const half_t* __restrict__ E, const half_t* __restrict__ vT,
    float* __restrict__ Pa) {
    __shared__ __align__(16) half_t As[128 * 32];
    __shared__ __align__(16) half_t Bs[128 * 32];
    const int tid = threadIdx.x;
    const int lane = tid & 63, wv = tid >> 6;
    const int wr = wv >> 1, wc = wv & 1;
    const int quad = lane >> 4, r = lane & 15;
    const int qsw = (quad ^ ((r >> 1) & 3)) * 8;
    const int mb = blockIdx.x * 128, nb = blockIdx.y * 128;   // swapped
    const int b = blockIdx.z >> 2, c = blockIdx.z & 3;
    const int kbeg = c * 512;
    const int kend = min(mb + 128, kbeg + 512);
    if (kend <= kbeg) return;

    const half_t* Ab = E + (long long)b * TT;
    const half_t* Bb = vT + (long long)b * Tk;
    float* Pc = Pa + (long long)blockIdx.z * TD;
    f32x4 acc[4][4] = {};
    const int srow = tid >> 2, skq = SKQ(tid);
    const int wbase = (tid & 192) * 8;
    for (int k0 = kbeg; k0 < kend; k0 += 32) {
#pragma unroll
        for (int rnd = 0; rnd < 2; rnd++) {
            int row = rnd * 64 + srow;
            glds16(Ab + (long long)(mb + row) * Tk + k0 + skq, As + rnd * 2048 + wbase);
            glds16(Bb + (long long)(nb + row) * BTk + k0 + skq, Bs + rnd * 2048 + wbase);
        }
        __syncthreads();
        half8 bfr[4];
#pragma unroll
        for (int ni = 0; ni < 4; ni++)
            bfr[ni] = *(const half8*)&Bs[(wc * 64 + ni * 16 + r) * 32 + qsw];
#pragma unroll
        for (int mi = 0; mi < 4; mi++) {
            half8 afr = *(const half8*)&As[(wr * 64 + mi * 16 + r) * 32 + qsw];
#pragma unroll
            for (int ni = 0; ni < 4; ni++)
                acc[mi][ni] = __builtin_amdgcn_mfma_f32_16x16x32_f16(afr, bfr[ni], acc[mi][ni], 0, 0, 0);
        }
        __syncthreads();
    }
#pragma unroll
    for (int mi = 0; mi < 4; mi++)
#pragma unroll
        for (int ni = 0; ni < 4; ni++) {
            int row0 = mb + wr * 64 + mi * 16 + quad * 4;
            int col = nb + wc * 64 + ni * 16 + r;
#pragma unroll
            for (int rr = 0; rr < 4; rr++)
                Pc[(long long)(row0 + rr) * Dk + col] = acc[mi][ni][rr];
        }
}

// ---------------------------------------------------------------------------
// Fused dual fp16 GEMM v2 (r15): 256 thr, 4 waves as 2x2, wave tile 64x64,
// BK=64 double-staged. LDS-read:MFMA ratio 0.5 (was 0.75); 8 barriers (was 16).
// Staging: lane L of a wave covers rows [band+L>>3], octet position L&7 holding
// global octet (L&7)^(L>>3) -> reader octet g at position g^(R&7): conflict-free.
// XCD remap kept (r14: FETCH 137->49 MB).
__global__ __launch_bounds__(256, 2) void dual_gemm(
    const half_t* __restrict__ A1,   // vf  [BT][D]
    const half_t* __restrict__ A2,   // lnf [BT][D]
    const half_t* __restrict__ dxT,  // [Nk][D]
    const half_t* __restrict__ dyT,  // [Nk][D]
    half_t* __restrict__ C) {        // y16 [BT][Nk]
    __shared__ __align__(16) half_t As1[128 * 64];
    __shared__ __align__(16) half_t As2[128 * 64];
    __shared__ __align__(16) half_t Bs1[128 * 64];
    __shared__ __align__(16) half_t Bs2[128 * 64];
    const int tid = threadIdx.x;
    const int lane = tid & 63, wv = tid >> 6;     // 4 waves
    const int wr = wv >> 1, wc = wv & 1;          // 2 x 2 wave grid
    const int quad = lane >> 4, r = lane & 15;
    // block remap: grid (16,64,4) flat -> (m,n,h), xcd-major
    const int flat = blockIdx.x + 16 * (blockIdx.y + 64 * blockIdx.z);
    const int xcd = flat & 7, j = flat >> 3;
    const int mt = (xcd >> 2) * 32 + (j >> 4);          // 0..63
    const int nt = (xcd & 3) * 4 + (j & 3);             // 0..15
    const int h  = (j >> 2) & 3;                        // 0..3
    const int mb = mt * 128, nb = nt * 128;
    const half_t* B1 = dxT + (long long)h * MHk * Dk;
    const half_t* B2 = dyT + (long long)h * MHk * Dk;

    f32x4 accX[4][4] = {};
    f32x4 accY[4][4] = {};
    const int srow8 = lane >> 3;              // 0..7 within 8-row group
    const int soct  = (lane & 7) ^ srow8;     // XOR'd source octet
    for (int k0 = 0; k0 < Dk; k0 += 64) {
#pragma unroll
        for (int c = 0; c < 4; c++) {
            int row = wv * 32 + c * 8;        // wave-uniform band base
            long long ga = (long long)(mb + row + srow8) * Dk + k0 + soct * 8;
            long long gb = (long long)(nb + row + srow8) * Dk + k0 + soct * 8;
            glds16(A1 + ga, As1 + row * 64);
            glds16(A2 + ga, As2 + row * 64);
            glds16(B1 + gb, Bs1 + row * 64);
            glds16(B2 + gb, Bs2 + row * 64);
        }
        __syncthreads();
#pragma unroll
        for (int sub = 0; sub < 2; sub++) {
            half8 b1f[4], b2f[4];
#pragma unroll
            for (int ni = 0; ni < 4; ni++) {
                int R = wc * 64 + ni * 16 + r;
                int pos = ((sub * 4 + quad) ^ (R & 7)) * 8;
                b1f[ni] = *(const half8*)&Bs1[R * 64 + pos];
                b2f[ni] = *(const half8*)&Bs2[R * 64 + pos];
            }
#pragma unroll
            for (int mi = 0; mi < 4; mi++) {
                int R = wr * 64 + mi * 16 + r;
                int pos = ((sub * 4 + quad) ^ (R & 7)) * 8;
                half8 a1 = *(const half8*)&As1[R * 64 + pos];
                half8 a2 = *(const half8*)&As2[R * 64 + pos];
#pragma unroll
                for (int ni = 0; ni < 4; ni++) {
                    accX[mi][ni] = __builtin_amdgcn_mfma_f32_16x16x32_f16(a1, b1f[ni], accX[mi][ni], 0, 0, 0);
                    accY[mi][ni] = __builtin_amdgcn_mfma_f32_16x16x32_f16(a2, b2f[ni], accY[mi][ni], 0, 0, 0);
                }
            }
        }
        __syncthreads();
    }
#pragma unroll
    for (int mi = 0; mi < 4; mi++)
#pragma unroll
        for (int ni = 0; ni < 4; ni++) {
            int row0 = mb + wr * 64 + mi * 16 + quad * 4;
            int col = h * MHk + nb + wc * 64 + ni * 16 + r;
#pragma unroll
            for (int rr = 0; rr < 4; rr++) {
                float val = fmaxf(accY[mi][ni][rr], 0.f) * fmaxf(accX[mi][ni][rr], 0.f);
                C[(long long)(row0 + rr) * Nk + col] = (half_t)val;
            }
        }
}

// ---------------------------------------------------------------------------
// Update: Pu[z] = y @ enc over K-chunk z*2048, 128x128 swizzled, partials.
// x = m-tile (A-locality grid, r14 win).
__global__ __launch_bounds__(256) void gemm128u(
    const half_t* __restrict__ A, const half_t* __restrict__ B,
    float* __restrict__ Pu) {
    __shared__ __align__(16) half_t As[128 * 32];
    __shared__ __align__(16) half_t Bs[128 * 32];
    const int tid = threadIdx.x;
    const int lane = tid & 63, wv = tid >> 6;
    const int wr = wv >> 1, wc = wv & 1;
    const int quad = lane >> 4, r = lane & 15;
    const int qsw = (quad ^ ((r >> 1) & 3)) * 8;
    const int mb = blockIdx.x * 128, nb = blockIdx.y * 128;   // swapped
    const int kbeg = blockIdx.z * 2048;
    float* Pc = Pu + (long long)blockIdx.z * BTD;

    f32x4 acc[4][4] = {};
    const int srow = tid >> 2, skq = SKQ(tid);
    const int wbase = (tid & 192) * 8;
    for (int k0 = kbeg; k0 < kbeg + 2048; k0 += 32) {
#pragma unroll
        for (int rnd = 0; rnd < 2; rnd++) {
            int row = rnd * 64 + srow;
            glds16(A + (long long)(mb + row) * Nk + k0 + skq, As + rnd * 2048 + wbase);
            glds16(B + (long long)(nb + row) * Nk + k0 + skq, Bs + rnd * 2048 + wbase);
        }
        __syncthreads();
        half8 bfr[4];
#pragma unroll
        for (int ni = 0; ni < 4; ni++)
            bfr[ni] = *(const half8*)&Bs[(wc * 64 + ni * 16 + r) * 32 + qsw];
#pragma unroll
        for (int mi = 0; mi < 4; mi++) {
            half8 afr = *(const half8*)&As[(wr * 64 + mi * 16 + r) * 32 + qsw];
#pragma unroll
            for (int ni = 0; ni < 4; ni++)
                acc[mi][ni] = __builtin_amdgcn_mfma_f32_16x16x32_f16(afr, bfr[ni], acc[mi][ni], 0, 0, 0);
        }
        __syncthreads();
    }
#pragma unroll
    for (int mi = 0; mi < 4; mi++)
#pragma unroll
        for (int ni = 0; ni < 4; ni++) {
            int row0 = mb + wr * 64 + mi * 16 + quad * 4;
            int col = nb + wc * 64 + ni * 16 + r;
#pragma unroll
            for (int rr = 0; rr < 4; rr++)
                Pc[(long long)(row0 + rr) * Dk + col] = acc[mi][ni][rr];
        }
}

// ---------------------------------------------------------------------------
// Plain fp16 64x64 async GEMM, swizzled, fp32 store — readout.
__global__ __launch_bounds__(256) void gemm64h(
    const half_t* __restrict__ A, int lda,
    const half_t* __restrict__ B, int ldb,
    float* __restrict__ C, int ldc, int K) {
    __shared__ __align__(16) half_t As[64 * 32];
    __shared__ __align__(16) half_t Bs[64 * 32];
    const int tid = threadIdx.x;
    const int lane = tid & 63, wv = tid >> 6;
    const int wr = wv >> 1, wc = wv & 1;
    const int quad = lane >> 4, r = lane & 15;
    const int qsw = (quad ^ ((r >> 1) & 3)) * 8;
    const int mb = blockIdx.y * 64, nb = blockIdx.x * 64;

    f32x4 acc[2][2] = {};
    const int srow = tid >> 2, skq = SKQ(tid);
    const int wbase = (tid & 192) * 8;
    for (int k0 = 0; k0 < K; k0 += 32) {
        glds16(A + (long long)(mb + srow) * lda + k0 + skq, As + wbase);
        glds16(B + (long long)(nb + srow) * ldb + k0 + skq, Bs + wbase);
        __syncthreads();
        half8 b0 = *(const half8*)&Bs[(wc * 32 +  0 + r) * 32 + qsw];
        half8 b1 = *(const half8*)&Bs[(wc * 32 + 16 + r) * 32 + qsw];
#pragma unroll
        for (int mi = 0; mi < 2; mi++) {
            half8 afr = *(const half8*)&As[(wr * 32 + mi * 16 + r) * 32 + qsw];
            acc[mi][0] = __builtin_amdgcn_mfma_f32_16x16x32_f16(afr, b0, acc[mi][0], 0, 0, 0);
            acc[mi][1] = __builtin_amdgcn_mfma_f32_16x16x32_f16(afr, b1, acc[mi][1], 0, 0, 0);
        }
        __syncthreads();
    }
#pragma unroll
    for (int mi = 0; mi < 2; mi++)
#pragma unroll
        for (int ni = 0; ni < 2; ni++) {
            int row0 = mb + wr * 32 + mi * 16 + quad * 4;
            int col = nb + wc * 32 + ni * 16 + r;
#pragma unroll
            for (int rr = 0; rr < 4; rr++)
                C[(long long)(row0 + rr) * ldc + col] = acc[mi][ni][rr];
        }
}

// ---------------------------------------------------------------------------
extern "C" void kernel_launch(void* const* d_in, const int* in_sizes, int n_in,
                              void* d_out, int out_size, void* d_ws, size_t ws_size,
                              hipStream_t stream) {
    (void)in_sizes; (void)n_in; (void)out_size; (void)ws_size;
    const int* idx = (const int*)d_in[0];
    float* out = (float*)d_out;

    char* ws = (char*)d_ws;
    float*  v32  = (float*) (ws);                   //   8 MiB [8192][256]
    half_t* vf   = (half_t*)(ws + (  8ll << 20));   //   4
    half_t* qf   = (half_t*)(ws + ( 12ll << 20));   //   4
    half_t* vT   = (half_t*)(ws + ( 16ll << 20));   //   4 [256][8192]
    half_t* lnf  = (half_t*)(ws + ( 20ll << 20));   //   4
    half_t* E    = (half_t*)(ws + ( 24ll << 20));   //  32 [4][2048][2048] f16
    float*  Pa   = (float*) (ws + ( 56ll << 20));   //  32 [16][2048][256] f32
    float*  Pu   = (float*) (ws + ( 24ll << 20));   //  64 [4][8192][256] f32 (aliases E+Pa, phase-disjoint)
    half_t* y16  = (half_t*)(ws + ( 88ll << 20));   // 128 [8192][8192] f16
    half_t* dxT  = (half_t*)(ws + (216ll << 20));   //   4 [Nk][D]
    half_t* dyT  = (half_t*)(ws + (220ll << 20));   //   4
    half_t* eT   = (half_t*)(ws + (224ll << 20));   //   4 [256][8192]
    half_t* roT  = (half_t*)(ws + (228ll << 20));   // 128 KiB [256][256]
    int*    flag = (int*)   (ws + (228ll << 20) + (256ll << 10));
    // total ~229 MiB (ws 256 MiB)

    sniff_kernel<<<1, 256, 0, stream>>>((const unsigned short*)d_in[1], flag);
    tr_cvt16_kernel<<<dim3(MHk / 32, Dk / 32, 4), 256, 0, stream>>>(
        d_in[3], flag, dxT, Dk, MHk, (long long)Dk * MHk, (long long)Dk * MHk);
    tr_cvt16_kernel<<<dim3(MHk / 32, Dk / 32, 4), 256, 0, stream>>>(
        d_in[4], flag, dyT, Dk, MHk, (long long)Dk * MHk, (long long)Dk * MHk);
    tr_cvt16_kernel<<<dim3(Dk / 32, Nk / 32, 1), 256, 0, stream>>>(
        d_in[2], flag, eT, Nk, Dk, 0, 0);
    tr_cvt16_kernel<<<dim3(Dk / 32, Dk / 32, 1), 256, 0, stream>>>(
        d_in[5], flag, roT, Dk, Dk, 0, 0);

    embed_ln_kernel<<<BTk, 256, 0, stream>>>(idx, d_in[1], flag, v32, vf, qf);

    for (int l = 0; l < LAYERS; l++) {
        trv_kernel<<<dim3(Dk / 32, BTk / 32), 256, 0, stream>>>(v32, vT);
        // E[b] = tril(Qr Qr^T), fp16, all 4 batches (upper blocks skipped)
        gemm128e<<<dim3(Tk / 128, Tk / 128, 4), 256, 0, stream>>>(qf, E);
        // Pa[b*4+c] = E_chunk @ v (partials; dead causal chunks skipped)
        gemm128a<<<dim3(Tk / 128, Dk / 128, 16), 256, 0, stream>>>(E, vT, Pa);
        // lnf = LN(sum of alive partials)
        ln_rows_kernel<<<BTk, 256, 0, stream>>>(Pa, lnf);
        // y (all 4 heads, one dispatch, XCD-remapped, 64x64 wave tiles)
        dual_gemm<<<dim3(MHk / 128, BTk / 128, 4), 256, 0, stream>>>(
            vf, lnf, dxT, dyT, y16);
        // Pu[z] = y @ enc, K-chunk 2048 (partials; A-locality grid)
        gemm128u<<<dim3(BTk / 128, Dk / 128, 4), 256, 0, stream>>>(y16, eT, Pu);
        // v += LN(sum of partials); rope fused -> qf for next layer
        add_ln_kernel<<<BTk, 256, 0, stream>>>(Pu, v32, vf, qf);
    }
    // logits = vf @ roT^T -> fp32 out
    gemm64h<<<dim3(Dk / 64, BTk / 64), 256, 0, stream>>>(
        vf, Dk, roT, Dk, out, Dk, Dk);
}